// Round 1
// baseline (804.383 us; speedup 1.0000x reference)
//
#include <hip/hip_runtime.h>

#define V 128
#define D 20
#define NUM_EMB (V * V * V)

__global__ __launch_bounds__(256) void dense_grid_enc_kernel(
    const float* __restrict__ x, const float* __restrict__ grid,
    float* __restrict__ out, int N)
{
    int i = blockIdx.x * blockDim.x + threadIdx.x;
    if (i >= N) return;

    float px = x[3 * i + 0];
    float py = x[3 * i + 1];
    float pz = x[3 * i + 2];

    // gp = floor((p - DOM_LO)/DOM_LEN * V) = floor((p+1)*64)
    float fx = (px + 1.0f) * 64.0f;
    float fy = (py + 1.0f) * 64.0f;
    float fz = (pz + 1.0f) * 64.0f;
    int ix = (int)floorf(fx);
    int iy = (int)floorf(fy);
    int iz = (int)floorf(fz);

    // Reference: x1 = ix/V*DOM_LEN + DOM_LO ; x2 = (ix+1)/V*DOM_LEN + DOM_LO
    // (x2 - x1) == 2/128 == 1/64 exactly in fp32, so /(x2-x1) == *64
    float x1 = (float)ix * (2.0f / 128.0f) - 1.0f;
    float x2 = (float)(ix + 1) * (2.0f / 128.0f) - 1.0f;
    float y1 = (float)iy * (2.0f / 128.0f) - 1.0f;
    float y2 = (float)(iy + 1) * (2.0f / 128.0f) - 1.0f;
    float z1 = (float)iz * (2.0f / 128.0f) - 1.0f;
    float z2 = (float)(iz + 1) * (2.0f / 128.0f) - 1.0f;

    float wx1 = (px - x1) * 64.0f;
    float wx0 = (x2 - px) * 64.0f;
    float wy1 = (py - y1) * 64.0f;
    float wy0 = (y2 - py) * 64.0f;
    float wz1 = (pz - z1) * 64.0f;
    float wz0 = (z2 - pz) * 64.0f;

    int f000 = ix + iy * V + iz * V * V;

    int flats[8];
    flats[0] = f000;                 // (0,0,0)
    flats[1] = f000 + 1;             // (1,0,0)
    flats[2] = f000 + V;             // (0,1,0)
    flats[3] = f000 + V + 1;         // (1,1,0)
    flats[4] = f000 + V * V;         // (0,0,1)
    flats[5] = f000 + V * V + 1;     // (1,0,1)
    flats[6] = f000 + V * V + V;     // (0,1,1)
    flats[7] = f000 + V * V + V + 1; // (1,1,1)

    // JAX gather clamps out-of-bounds indices (iz+1 can hit 128 -> flat >= NUM_EMB)
    #pragma unroll
    for (int c = 0; c < 8; c++) {
        if (flats[c] > NUM_EMB - 1) flats[c] = NUM_EMB - 1;
    }

    float w[8];
    w[0] = wx0 * wy0 * wz0;
    w[1] = wx1 * wy0 * wz0;
    w[2] = wx0 * wy1 * wz0;
    w[3] = wx1 * wy1 * wz0;
    w[4] = wx0 * wy0 * wz1;
    w[5] = wx1 * wy0 * wz1;
    w[6] = wx0 * wy1 * wz1;
    w[7] = wx1 * wy1 * wz1;

    float4 acc[5];
    #pragma unroll
    for (int k = 0; k < 5; k++) acc[k] = make_float4(0.f, 0.f, 0.f, 0.f);

    #pragma unroll
    for (int c = 0; c < 8; c++) {
        const float4* row = (const float4*)(grid + (size_t)flats[c] * D);
        float wc = w[c];
        #pragma unroll
        for (int k = 0; k < 5; k++) {
            float4 q = row[k];
            acc[k].x += wc * q.x;
            acc[k].y += wc * q.y;
            acc[k].z += wc * q.z;
            acc[k].w += wc * q.w;
        }
    }

    float4* orow = (float4*)(out + (size_t)i * D);
    #pragma unroll
    for (int k = 0; k < 5; k++) orow[k] = acc[k];
}

extern "C" void kernel_launch(void* const* d_in, const int* in_sizes, int n_in,
                              void* d_out, int out_size, void* d_ws, size_t ws_size,
                              hipStream_t stream) {
    const float* x = (const float*)d_in[0];
    const float* grid = (const float*)d_in[1];
    float* out = (float*)d_out;
    int N = in_sizes[0] / 3;

    int block = 256;
    int nblocks = (N + block - 1) / block;
    dense_grid_enc_kernel<<<nblocks, block, 0, stream>>>(x, grid, out, N);
}

// Round 3
// 364.712 us; speedup vs baseline: 2.2055x; 2.2055x over previous
//
#include <hip/hip_runtime.h>

#define V 128
#define D 20
#define NUM_EMB (V * V * V)

typedef float v4f __attribute__((ext_vector_type(4)));

// 5 threads per point: thread (i, k) computes float4 chunk k (floats 4k..4k+3)
// of output row i. Each thread issues 8 independent 16B gathers (one per
// corner) -> deep MLP; 5M threads -> 78k waves for latency hiding.
__global__ __launch_bounds__(320) void dense_grid_enc_kernel(
    const float* __restrict__ x, const float* __restrict__ grid,
    float* __restrict__ out, int N)
{
    int tid = threadIdx.x;            // 0..319
    int lp  = tid / 5;                // local point 0..63
    int k   = tid - lp * 5;           // chunk 0..4
    int i   = blockIdx.x * 64 + lp;   // global point
    if (i >= N) return;

    float px = x[3 * i + 0];
    float py = x[3 * i + 1];
    float pz = x[3 * i + 2];

    // gp = floor((p+1)*64); cell spacing is exactly 1/64 in fp32
    int ix = (int)floorf((px + 1.0f) * 64.0f);
    int iy = (int)floorf((py + 1.0f) * 64.0f);
    int iz = (int)floorf((pz + 1.0f) * 64.0f);

    float x1 = (float)ix * (2.0f / 128.0f) - 1.0f;
    float x2 = (float)(ix + 1) * (2.0f / 128.0f) - 1.0f;
    float y1 = (float)iy * (2.0f / 128.0f) - 1.0f;
    float y2 = (float)(iy + 1) * (2.0f / 128.0f) - 1.0f;
    float z1 = (float)iz * (2.0f / 128.0f) - 1.0f;
    float z2 = (float)(iz + 1) * (2.0f / 128.0f) - 1.0f;

    float wx1 = (px - x1) * 64.0f, wx0 = (x2 - px) * 64.0f;
    float wy1 = (py - y1) * 64.0f, wy0 = (y2 - py) * 64.0f;
    float wz1 = (pz - z1) * 64.0f, wz0 = (z2 - pz) * 64.0f;

    int f000 = ix + iy * V + iz * V * V;

    int flats[8];
    flats[0] = f000;
    flats[1] = f000 + 1;
    flats[2] = f000 + V;
    flats[3] = f000 + V + 1;
    flats[4] = f000 + V * V;
    flats[5] = f000 + V * V + 1;
    flats[6] = f000 + V * V + V;
    flats[7] = f000 + V * V + V + 1;

    // JAX gather clamps OOB (ix+1 etc. can push flat to NUM_EMB at the corner)
    #pragma unroll
    for (int c = 0; c < 8; c++) {
        if (flats[c] > NUM_EMB - 1) flats[c] = NUM_EMB - 1;
    }

    float w[8];
    w[0] = wx0 * wy0 * wz0;
    w[1] = wx1 * wy0 * wz0;
    w[2] = wx0 * wy1 * wz0;
    w[3] = wx1 * wy1 * wz0;
    w[4] = wx0 * wy0 * wz1;
    w[5] = wx1 * wy0 * wz1;
    w[6] = wx0 * wy1 * wz1;
    w[7] = wx1 * wy1 * wz1;

    // 8 independent 16B gathers — all issued before first use
    v4f q[8];
    #pragma unroll
    for (int c = 0; c < 8; c++) {
        q[c] = *(const v4f*)(grid + (size_t)flats[c] * D + 4 * k);
    }

    v4f acc = (v4f)(0.0f);
    #pragma unroll
    for (int c = 0; c < 8; c++) {
        acc += w[c] * q[c];
    }

    // out row i, chunk k: block-wide stores are one contiguous 5KB span
    __builtin_nontemporal_store(acc, (v4f*)(out + (size_t)i * D + 4 * k));
}

extern "C" void kernel_launch(void* const* d_in, const int* in_sizes, int n_in,
                              void* d_out, int out_size, void* d_ws, size_t ws_size,
                              hipStream_t stream) {
    const float* x = (const float*)d_in[0];
    const float* grid = (const float*)d_in[1];
    float* out = (float*)d_out;
    int N = in_sizes[0] / 3;

    int pts_per_block = 64;
    int nblocks = (N + pts_per_block - 1) / pts_per_block;
    dense_grid_enc_kernel<<<nblocks, 320, 0, stream>>>(x, grid, out, N);
}